// Round 6
// baseline (78.379 us; speedup 1.0000x reference)
//
#include <hip/hip_runtime.h>

typedef float f32x4 __attribute__((ext_vector_type(4)));

#define ZD      128      // feature dim (bytes per fp8 row, too)
#define BT      128      // block tile (128x128, 64x64 per wave)
#define D2_CUT  60.0f    // exact-path cutoff: exp(-30)~9e-14
#define D2_TRIG 70.0f    // trigger: fp8 dot err <= ~+-3 on d2 => skip implies
                         // true d2 >= 70-6 > D2_CUT (12-sigma data margin)

// async global->LDS DMA, 16B per lane; LDS dest = wave-uniform base + lane*16
__device__ __forceinline__ void async_copy16(const unsigned char* g,
                                             unsigned char* l) {
    __builtin_amdgcn_global_load_lds(
        (const __attribute__((address_space(1))) unsigned int*)g,
        (__attribute__((address_space(3))) unsigned int*)l,
        16, 0, 0);
}

// ---------------------------------------------------------------------------
// Kernel A (verified in R5): 1024 blocks x 8 rows -> 4 blocks/CU (R0's 256
// blocks = 1/CU was occupancy-starved for a 4 MB HBM read). ||z_i||^2 fp32
// exact, per-8-row min, z -> fp8 e4m3 (HW cvt_pk). Block 0 / wave 2: class
// counts, analytic diagonal, out[0] = diag*scale (identical double math).
// ---------------------------------------------------------------------------
__global__ __launch_bounds__(256) void dep_prep(
    const float* __restrict__ z, const int* __restrict__ s,
    float* __restrict__ sq, float* __restrict__ sqmin8,
    unsigned char* __restrict__ zb8, float* __restrict__ pvals,
    const float* __restrict__ norm, float* __restrict__ out, int N)
{
    __shared__ float part[8][33];
    const int tid  = threadIdx.x;
    const int wave = tid >> 6, lane = tid & 63;
    const int half = lane >> 5, c = lane & 31;
    const int r0   = blockIdx.x * 8;

    if (blockIdx.x == 0 && wave == 2) {
        int c0 = 0, c1 = 0, c2 = 0, c3 = 0;
        for (int it = lane; it < N / 4; it += 64) {
            int4 v = ((const int4*)s)[it];
            c0 += (v.x == 0) + (v.y == 0) + (v.z == 0) + (v.w == 0);
            c1 += (v.x == 1) + (v.y == 1) + (v.z == 1) + (v.w == 1);
            c2 += (v.x == 2) + (v.y == 2) + (v.z == 2) + (v.w == 2);
            c3 += (v.x == 3) + (v.y == 3) + (v.z == 3) + (v.w == 3);
        }
        #pragma unroll
        for (int off = 1; off < 64; off <<= 1) {
            c0 += __shfl_xor(c0, off, 64);
            c1 += __shfl_xor(c1, off, 64);
            c2 += __shfl_xor(c2, off, 64);
            c3 += __shfl_xor(c3, off, 64);
        }
        if (lane == 0) {
            const double n = (double)N;
            const double p0 = c0 / n, p1 = c1 / n, p2 = c2 / n, p3 = c3 / n;
            const double sump2 = p0*p0 + p1*p1 + p2*p2 + p3*p3;
            const double scale = (1.0 - exp(-1.0)) / ((double)norm[0] * n * n);
            pvals[0] = (float)p0; pvals[1] = (float)p1;
            pvals[2] = (float)p2; pvals[3] = (float)p3;
            pvals[4] = (float)sump2;
            pvals[5] = (float)scale;
            const double c2sum = (double)c0*c0 + (double)c1*c1
                               + (double)c2*c2 + (double)c3*c3;
            const double diag = n - c2sum / n;   // K_z[i,i] = 1 analytically
            out[0] = (float)(diag * scale);
        }
    }

    {
        const int rloc = wave * 2 + half;        // 0..7
        const int r    = r0 + rloc;
        float4 v = ((const float4*)z)[r * 32 + c];
        int pk = __builtin_amdgcn_cvt_pk_fp8_f32(v.x, v.y, 0, false);
        pk     = __builtin_amdgcn_cvt_pk_fp8_f32(v.z, v.w, pk, true);
        ((unsigned int*)zb8)[r * 32 + c] = (unsigned int)pk;
        part[rloc][c] = v.x*v.x + v.y*v.y + v.z*v.z + v.w*v.w;
    }
    __syncthreads();

    if (wave == 0 && lane < 8) {
        float sum = 0.f;
        #pragma unroll
        for (int k = 0; k < 32; ++k) sum += part[lane][k];   // conflict-free
        sq[r0 + lane] = sum;
        float mn = sum;
        #pragma unroll
        for (int off = 1; off < 8; off <<= 1)                // lanes 0..7
            mn = fminf(mn, __shfl_xor(mn, off, 64));
        if (lane == 0) sqmin8[blockIdx.x] = mn;
    }
}

// ---------------------------------------------------------------------------
// Kernel B: R0's measured-best 128x128 config VERBATIM (32 KB LDS, 4 blocks/
// CU, 16 waves/CU, swizzled DMA staging, fp8 MFMA, bound epilogue), plus two
// critical-path-latency fixes:
//  (1) triangle map via float sqrt + exact int fixups (R5-verified pattern;
//      all intermediates <= 16641 are float-exact) -- removes a slow f64
//      sqrt before DMA issue;
//  (2) epilogue sqmin prefetch: the 4x float4 sqmin8 loads issue BEFORE the
//      staging DMAs (complete during the vmcnt(0) drain, reduced after
//      MFMA) -- removes ~L3-latency from the per-block serial tail.
// sqmin granularity 32->8 rows: each 64-row slice min is over the identical
// row set as R0's fminf(sqmin[gA],sqmin[gA+1]) -> same bound value.
// ---------------------------------------------------------------------------
__global__ __launch_bounds__(256, 4) void dep_pair(
    const unsigned char* __restrict__ zb8, const float* __restrict__ sq,
    const float* __restrict__ sqmin8, const int* __restrict__ s,
    const float* __restrict__ pvals, float* __restrict__ out, int T)
{
    __shared__ unsigned char Apan[BT * ZD];   // 16KB
    __shared__ unsigned char Bpan[BT * ZD];   // 16KB

    const int tid  = threadIdx.x;
    const int wave = tid >> 6, lane = tid & 63;

    // block-uniform triangle map t -> (ti <= tj), float sqrt + exact fixup
    const int t = blockIdx.x;
    #define TRI_BASE(x) ((x) * T - ((x) * ((x) - 1)) / 2)
    const float sf = sqrtf((float)((2 * T + 1) * (2 * T + 1) - 8 * t));
    int ti = (int)(((float)(2 * T + 1) - sf) * 0.5f);
    if (ti < 0) ti = 0;
    if (ti > T - 1) ti = T - 1;
    while (ti + 1 < T && TRI_BASE(ti + 1) <= t) ++ti;
    while (ti > 0 && TRI_BASE(ti) > t) --ti;
    const int tj = ti + (t - TRI_BASE(ti));
    #undef TRI_BASE

    const int i0 = ti * BT, j0 = tj * BT;
    const int wi = wave >> 1, wj = wave & 1;
    const int l15 = lane & 15, quad = lane >> 4;
    const int ibase = i0 + wi * 64, jbase = j0 + wj * 64;

    // (2) early epilogue prefetch: 8-row norm mins for both 64-row slices
    // (gA,gB are multiples of 8 -> 16B-aligned float4 pairs)
    const f32x4 pa0 = *(const f32x4*)(sqmin8 + (ibase >> 3));
    const f32x4 pa1 = *(const f32x4*)(sqmin8 + (ibase >> 3) + 4);
    const f32x4 pb0 = *(const f32x4*)(sqmin8 + (jbase >> 3));
    const f32x4 pb1 = *(const f32x4*)(sqmin8 + (jbase >> 3) + 4);

    // async stage both panels: per wave 4+4 DMAs of 1KB (8 rows each).
    // LDS[row][c] = G[row][c ^ (row&7)]  (global-side swizzle; base uniform)
    {
        const unsigned char* gAp = zb8 + (size_t)i0 * ZD;
        const unsigned char* gBp = zb8 + (size_t)j0 * ZD;
        const int rl  = lane >> 3;          // row within 8-row group (0..7)
        const int cch = lane & 7;           // dest 16B-chunk within row
        const int gch = cch ^ rl;           // source chunk (row&7 == rl)
        #pragma unroll
        for (int k = 0; k < 4; ++k) {
            const int r0i = (wave * 4 + k) * 8;        // wave-uniform
            const size_t go = (size_t)(r0i + rl) * ZD + (gch << 4);
            async_copy16(gAp + go, Apan + r0i * ZD);
            async_copy16(gBp + go, Bpan + r0i * ZD);
        }
    }
    __syncthreads();   // vmcnt(0) drain; 3 co-resident blocks overlap

    f32x4 accv[4][4];
    #pragma unroll
    for (int a = 0; a < 4; ++a)
        #pragma unroll
        for (int b = 0; b < 4; ++b)
            accv[a][b] = (f32x4){0.f, 0.f, 0.f, 0.f};

    const int sub = (quad & 1) * 8;         // 8B half within 16B chunk
    #pragma unroll
    for (int kc = 0; kc < 4; ++kc) {
        long af[4], bfr[4];
        // orig chunk = kc*2 + quad/2; row&7 == l15&7 for all fragment rows
        const int ch = (kc * 2 + (quad >> 1)) ^ (l15 & 7);
        #pragma unroll
        for (int it = 0; it < 4; ++it) {
            const int row = wi * 64 + it * 16 + l15;
            af[it] = *(const long*)(Apan + row * ZD + (ch << 4) + sub);
        }
        #pragma unroll
        for (int jt = 0; jt < 4; ++jt) {
            const int row = wj * 64 + jt * 16 + l15;
            bfr[jt] = *(const long*)(Bpan + row * ZD + (ch << 4) + sub);
        }
        #pragma unroll
        for (int it = 0; it < 4; ++it)
            #pragma unroll
            for (int jt = 0; jt < 4; ++jt)
                accv[it][jt] = __builtin_amdgcn_mfma_f32_16x16x32_fp8_fp8(
                    af[it], bfr[jt], accv[it][jt], 0, 0, 0);
    }

    // ---- fast epilogue: wave-max of dots vs conservative d2 lower bound ----
    float m = -1e30f;
    #pragma unroll
    for (int it = 0; it < 4; ++it)
        #pragma unroll
        for (int jt = 0; jt < 4; ++jt) {
            const f32x4 v = accv[it][jt];
            m = fmaxf(m, fmaxf(fmaxf(v[0], v[1]), fmaxf(v[2], v[3])));
        }
    #pragma unroll
    for (int off = 1; off < 64; off <<= 1)
        m = fmaxf(m, __shfl_xor(m, off, 64));

    // reduce the prefetched 8-row mins (loads long since complete)
    const float sminA =
        fminf(fminf(fminf(pa0[0], pa0[1]), fminf(pa0[2], pa0[3])),
              fminf(fminf(pa1[0], pa1[1]), fminf(pa1[2], pa1[3])));
    const float sminB =
        fminf(fminf(fminf(pb0[0], pb0[1]), fminf(pb0[2], pb0[3])),
              fminf(fminf(pb1[0], pb1[1]), fminf(pb1[2], pb1[3])));
    const float bound = sminA + sminB - 2.0f * m;

    if (bound < D2_TRIG) {   // wave-uniform; diag quadrants + rare triggers
        const float p0 = pvals[0], p1 = pvals[1],
                    p2 = pvals[2], p3 = pvals[3];
        const float sump2 = pvals[4], scale = pvals[5];
        const float p[4] = {p0, p1, p2, p3};

        float sqj[4];
        #pragma unroll
        for (int jt = 0; jt < 4; ++jt) sqj[jt] = sq[jbase + jt * 16 + l15];

        float local = 0.f;
        #pragma unroll
        for (int it = 0; it < 4; ++it) {
            #pragma unroll
            for (int r = 0; r < 4; ++r) {
                const int i = ibase + it * 16 + quad * 4 + r;  // C/D row
                const float sqi = sq[i];
                #pragma unroll
                for (int jt = 0; jt < 4; ++jt) {
                    const int j = jbase + jt * 16 + l15;       // C/D col
                    float d2 = sqi + sqj[jt] - 2.0f * accv[it][jt][r];
                    d2 = fmaxf(d2, 0.0f);
                    if (d2 < D2_CUT && i != j) {
                        const int si = s[i], sj = s[j];
                        const float w = (si == sj ? 1.0f : 0.0f)
                                      - p[si] - p[sj] + sump2;
                        local += w * __expf(-0.5f * d2);
                    }
                }
            }
        }
        if (ti < tj) local *= 2.0f;   // off-diag tiles count both orders

        #pragma unroll
        for (int off = 32; off > 0; off >>= 1)
            local += __shfl_down(local, off, 64);
        if (lane == 0 && local != 0.0f)
            atomicAdd(out, local * scale);
    }
}

extern "C" void kernel_launch(void* const* d_in, const int* in_sizes, int n_in,
                              void* d_out, int out_size, void* d_ws, size_t ws_size,
                              hipStream_t stream)
{
    const float* z    = (const float*)d_in[0];
    const int*   s    = (const int*)d_in[1];
    const float* norm = (const float*)d_in[2];
    float* out = (float*)d_out;

    const int N = in_sizes[1];       // 8192
    const int T = N / BT;            // 64

    char* ws = (char*)d_ws;
    float*         pvals  = (float*)ws;                        // 6 floats @0
    float*         sq     = (float*)(ws + 64);                 // N floats
    float*         sqmin8 = (float*)(ws + 64 + (size_t)N * 4); // N/8 floats
    unsigned char* zb8    = (unsigned char*)(ws + 64 + (size_t)N * 4
                                             + (size_t)(N / 8) * 4); // 16B-aligned

    dep_prep<<<N / 8, 256, 0, stream>>>(z, s, sq, sqmin8, zb8, pvals,
                                        norm, out, N);
    const int nblocks = T * (T + 1) / 2;   // 2080
    dep_pair<<<nblocks, 256, 0, stream>>>(zb8, sq, sqmin8, s, pvals, out, T);
}